// Round 10
// baseline (378.486 us; speedup 1.0000x reference)
//
#include <hip/hip_runtime.h>
#include <cstdint>

// Problem constants (fixed by setup_inputs): B=8, n=m=2048, iters=20.
#define BB 8
#define NN 2048
#define MM 2048
#define ITERS 20

typedef unsigned long long u64;

// 22-node fused structure (pack + 20 iter + final), r4-proven semantics
// (r4 passed absmax 0) with the per-eval key stream replaced by a per-round
// BITMASK so the hot scan stays 16 B/eval + ~4 VALU:
//   - kernel it's bidders post tag-(it+1) keys into pb_write AND set bit j1
//     in mask row it+1 (one atomicOr per bid).
//   - kernel it's scanning waves read mask row it (256 B preloaded into one
//     VGPR/lane); per 64-object strip: 1 shfl + and. Only fresh-bid objects
//     (bit set <=> tag==it key in pb_read) pay a scattered u64 key load:
//     pr = p2w_old.w + incr — the exact reference add.
//   - writer blocks (blk<64) fold tag==it keys into p2w_new (one round
//     behind, r4-identical); status is O(1)/point (mask bit for eviction,
//     key winner-field for bid outcome).
// NO in-kernel cross-block sync (r2/r7 lesson). it=0 uses the pristine r6
// 16 B/eval loop (no mask, everyone bids).
//
// Workspace (bytes):
//   p2w    float4[2][B*M]  xyz2 + price in .w   off 0        524288
//   pbuf   u64[2][B*M]     tagged bid keys      off 524288   262144
//   assign int[2][B*N]     point -> object      off 786432   131072
//   bidt   int[B*N]        last bid target      off 917504    65536
//   mask   u32[21][8][64]  per-round fresh bits off 983040    43008
// total 1026048 (< 1 MiB).
//
// Bid key: (tag << 43) | (float_bits(incr) << 11) | (2047 - i)
//   tag = it+1; incr > 0 => float bit order == value order; (2047-i) gives
//   the reference's min-index tie-break. Buffer rotation (kernel it):
//   p2w_old=p2w[it&1], p2w_new=p2w[(it+1)&1]; pb_read=pbuf[(it+1)&1],
//   pb_write=pbuf[it&1]; assign_old=assign[it&1], assign_new=[(it+1)&1].

__global__ __launch_bounds__(256) void pack_kernel(
    const float* __restrict__ xyz2, float4* __restrict__ p2w,
    u64* __restrict__ pbuf, unsigned* __restrict__ mask) {
  int idx = blockIdx.x * 256 + threadIdx.x;  // [0, B*M)
  p2w[idx] = make_float4(xyz2[idx * 3], xyz2[idx * 3 + 1],
                         xyz2[idx * 3 + 2], 0.f);
  pbuf[idx] = 0ULL;
  pbuf[BB * MM + idx] = 0ULL;
  if (idx < 21 * 8 * 64) mask[idx] = 0u;
}

// One wave per point; 4 waves/block, 4096 blocks (512 per batch).
__global__ __launch_bounds__(256) void iter_kernel(
    const float* __restrict__ xyz1,
    const float4* __restrict__ p2w_old, float4* __restrict__ p2w_new,
    const float* __restrict__ epsp,
    const u64* __restrict__ pb_read, u64* __restrict__ pb_write,
    const int* __restrict__ assign_old, int* __restrict__ assign_new,
    int* __restrict__ bidt, unsigned* __restrict__ mask, int it) {
#pragma clang fp contract(off)
  const int blk = blockIdx.x;            // [0, 4096)
  const int b = blk & 7;                 // batch affinity (512 blocks/batch)
  const int wave = threadIdx.x >> 6;
  const int lane = threadIdx.x & 63;
  const int i = ((blk >> 3) << 2) + wave;
  const int gi = b * NN + i;
  const u64* keys = pb_read + b * MM;

  // ---- writer duty (blk < 64): p2w_new = p2w_old + fold(tag==it) ----
  if (blk < 64) {
    int idx = blk * 256 + threadIdx.x;   // covers [0, B*M)
    float4 q = p2w_old[idx];
    if (it > 0) {
      u64 k = pb_read[idx];
      if ((int)(k >> 43) == it)
        q.w = q.w + __uint_as_float((unsigned)(k >> 11));  // reference add
    }
    p2w_new[idx] = q;
  }

  // ---- status (wave-uniform; O(1) loads) ----
  const unsigned* mrow = mask + (size_t)it * 512 + b * 64;
  bool need_bid;
  int cur = -1;
  if (it == 0) {
    need_bid = true;
  } else {
    int a_old = assign_old[gi];
    if (a_old >= 0) {
      // evicted iff object a_old got a fresh (tag==it) bid
      unsigned mw = mrow[a_old >> 5];
      need_bid = (mw >> (a_old & 31)) & 1u;
      if (!need_bid) cur = a_old;
    } else {
      int jt = bidt[gi];                 // we bid last kernel
      u64 k = keys[jt];
      if ((2047 - (int)(k & 0x7FF)) == i) { need_bid = false; cur = jt; }
      else need_bid = true;              // outbid
    }
  }
  if (lane == 0) assign_new[gi] = need_bid ? -1 : cur;
  if (!need_bid) return;                 // wave-uniform exit

  // ---- bid: top-2 scan, 16 B/eval + rare fresh-key fold ----
  const float eps = *epsp;
  const float* x1p = xyz1 + (size_t)gi * 3;
  float x1 = x1p[0], y1 = x1p[1], z1 = x1p[2];
  const float4* pold = p2w_old + b * MM;
  const float NEG_INF = __int_as_float(0xff800000);
  float v1 = NEG_INF, v2 = NEG_INF;
  int j1 = 0;

  if (it == 0) {
#pragma unroll 4
    for (int t = 0; t < MM / 64; ++t) {
      int j = (t << 6) + lane;
      float4 q = pold[j];                // xyz + price, one 16B load
      float dx = x1 - q.x;
      float dy = y1 - q.y;
      float dz = z1 - q.z;
      float c = dx * dx;
      c = c + dy * dy;                   // contract(off): matches numpy
      c = c + dz * dz;
      float v = -c - q.w;               // -cost - price, reference order
      bool c1 = v > v1;
      bool c2 = v > v2;
      v2 = c1 ? v1 : (c2 ? v : v2);
      v1 = c1 ? v : v1;
      j1 = c1 ? j : j1;
    }
  } else {
    unsigned myword = mrow[lane];        // lane L holds mask word L
    unsigned lanebit = 1u << (lane & 31);
#pragma unroll 4
    for (int t = 0; t < MM / 64; ++t) {
      int j = (t << 6) + lane;
      float4 q = pold[j];
      float pr = q.w;
      unsigned mw = __shfl(myword, (t << 1) + (lane >> 5), 64);
      if (mw & lanebit) {                // fresh tag==it bid on j (rare)
        u64 k = keys[j];
        pr = pr + __uint_as_float((unsigned)(k >> 11));  // reference add
      }
      float dx = x1 - q.x;
      float dy = y1 - q.y;
      float dz = z1 - q.z;
      float c = dx * dx;
      c = c + dy * dy;
      c = c + dz * dz;
      float v = -c - pr;
      bool c1 = v > v1;
      bool c2 = v > v2;
      v2 = c1 ? v1 : (c2 ? v : v2);
      v1 = c1 ? v : v1;
      j1 = c1 ? j : j1;
    }
  }
  // butterfly top-2 merge across lanes, tie-break min j on equal v1
  for (int o = 1; o < 64; o <<= 1) {
    float ov1 = __shfl_xor(v1, o, 64);
    float ov2 = __shfl_xor(v2, o, 64);
    int oj1 = __shfl_xor(j1, o, 64);
    bool ow = (ov1 > v1) || (ov1 == v1 && oj1 < j1);
    float loser = ow ? v1 : ov1;
    v1 = ow ? ov1 : v1;
    j1 = ow ? oj1 : j1;
    v2 = fmaxf(fmaxf(v2, ov2), loser);
  }
  if (lane == 0) {
    float incr = (v1 - v2) + eps;        // top1 - top2 + eps
    u64 key = ((u64)(unsigned)(it + 1) << 43) |
              ((u64)__float_as_uint(incr) << 11) |
              (u64)(unsigned)(2047 - i);
    atomicMax(&pb_write[b * MM + j1], key);
    bidt[gi] = j1;
    atomicOr(&mask[(size_t)(it + 1) * 512 + b * 64 + (j1 >> 5)],
             1u << (j1 & 31));
  }
}

// Final: resolve tag-ITERS bids per point (r4-identical), emit dist+assign.
__global__ __launch_bounds__(256) void final_kernel(
    const float* __restrict__ xyz1, const float4* __restrict__ p2f4,
    const u64* __restrict__ pb_last, const int* __restrict__ assign_old,
    const int* __restrict__ bidt, float* __restrict__ out) {
#pragma clang fp contract(off)
  int idx = blockIdx.x * 256 + threadIdx.x;  // [0, B*N)
  int b = idx >> 11, i = idx & (NN - 1);
  const u64* keys = pb_last + b * MM;

  int a_old = assign_old[idx];
  int cur;
  if (a_old >= 0) {
    u64 k = keys[a_old];
    cur = ((int)(k >> 43) == ITERS) ? -1 : a_old;   // evicted at the end?
  } else {
    int jt = bidt[idx];
    u64 k = keys[jt];
    cur = ((2047 - (int)(k & 0x7FF)) == i) ? jt : -1;
  }

  float d = 0.f;
  if (cur >= 0) {
    float4 q = p2f4[b * MM + cur];
    float dx = xyz1[idx * 3 + 0] - q.x;
    float dy = xyz1[idx * 3 + 1] - q.y;
    float dz = xyz1[idx * 3 + 2] - q.z;
    d = dx * dx;
    d = d + dy * dy;
    d = d + dz * dz;
  }
  out[idx] = d;
  out[BB * NN + idx] = (float)cur;       // assignment as float32 values
}

extern "C" void kernel_launch(void* const* d_in, const int* in_sizes, int n_in,
                              void* d_out, int out_size, void* d_ws, size_t ws_size,
                              hipStream_t stream) {
  const float* xyz1 = (const float*)d_in[0];
  const float* xyz2 = (const float*)d_in[1];
  const float* eps  = (const float*)d_in[2];
  // d_in[3] = iters (fixed at 20 by setup_inputs); hard-coded for capture.
  float* out = (float*)d_out;

  char* ws = (char*)d_ws;
  float4* p2w = (float4*)ws;                       // [2][B*M]
  u64* pbuf = (u64*)(ws + 524288);                 // [2][B*M]
  int* assign = (int*)(ws + 786432);               // [2][B*N]
  int* bidt = (int*)(ws + 917504);                 // [B*N]
  unsigned* mask = (unsigned*)(ws + 983040);       // [21][8][64]

  pack_kernel<<<BB * MM / 256, 256, 0, stream>>>(xyz2, p2w, pbuf, mask);

  for (int it = 0; it < ITERS; ++it) {
    const float4* po = p2w + (size_t)(it & 1) * BB * MM;
    float4* pn = p2w + (size_t)((it + 1) & 1) * BB * MM;
    const u64* pr = pbuf + (size_t)((it + 1) & 1) * BB * MM;
    u64* pw = pbuf + (size_t)(it & 1) * BB * MM;
    const int* ao = assign + (size_t)(it & 1) * BB * NN;
    int* an = assign + (size_t)((it + 1) & 1) * BB * NN;
    iter_kernel<<<4096, 256, 0, stream>>>(xyz1, po, pn, eps, pr, pw, ao, an,
                                          bidt, mask, it);
  }

  // kernel 19 wrote pbuf[1] (tag 20) and assign[0]
  final_kernel<<<BB * NN / 256, 256, 0, stream>>>(
      xyz1, p2w, pbuf + (size_t)(BB * MM), assign, bidt, out);
}

// Round 11
// 315.116 us; speedup vs baseline: 1.2011x; 1.2011x over previous
//
#include <hip/hip_runtime.h>
#include <cstdint>

// Problem constants (fixed by setup_inputs): B=8, n=m=2048, iters=20.
#define BB 8
#define NN 2048
#define MM 2048
#define ITERS 20

typedef unsigned long long u64;

// Skeleton = r6 champion (282 us; 43 nodes, 1 wave/point, 16 B/eval scan,
// price in p2w.w, tagged u64 bid keys, NO in-kernel cross-block sync).
// New: exact candidate pruning with monotone-price certificates.
//   - Every full scan is also a REFRESH: lane L stores its stripe top-1 as
//     cand = {negc = -c, j} (so future val = negc - price is the verbatim
//     reference op) and the wave stores bound[gi] = max_L (stripe runner-up
//     val at refresh prices).
//   - Prices only increase (incr = top1-top2+eps > 0), so bound remains an
//     upper bound on every non-candidate's value forever after refresh.
//   - Cert check: top-2 over the 64 candidates at CURRENT prices; if
//     in-cand v2 > bound (strict), every outside value <= bound < v2, so
//     the candidate top-2 equals the full-scan top-2 exactly (values,
//     argmax, min-index tie-break; dangerous ties fail the cert and fall
//     back). Cert fail -> full scan + refresh (bit-identical to r6).
//
// Workspace layout (bytes):
//   p2w    float4[B*M]    xyz2 + price in .w   off 0        262144
//   pbuf   u64[B*M]       tagged bid keys      off 262144   131072
//   inv    int[B*M]       object -> owner      off 393216    65536
//   assign int[B*N]       point  -> object     off 458752    65536
//   bound  f32[B*N]       cert bounds          off 524288    65536
//   cand   float2[B*N*64] {negc, j} per lane   off 589824  8388608
// total 8978432 bytes; if ws_size is smaller, use_cand=0 -> exact r6 path.
//
// Bid key: (tag << 43) | (float_bits(incr) << 11) | (2047 - i)
//   tag = it+1 (0 = empty); fresh tags dominate stale under atomicMax so
//   pbuf is never reset. incr > 0 => float bit order == value order;
//   (2047-i) = min-index tie-break (reference min-winner semantics).

__global__ __launch_bounds__(256) void pack_kernel(
    const float* __restrict__ xyz2, float4* __restrict__ p2w,
    u64* __restrict__ pbuf, int* __restrict__ inv, int* __restrict__ assign) {
  int idx = blockIdx.x * 256 + threadIdx.x;  // [0, B*M)
  p2w[idx] = make_float4(xyz2[idx * 3], xyz2[idx * 3 + 1],
                         xyz2[idx * 3 + 2], 0.f);
  pbuf[idx] = 0ULL;      // tag 0 = empty; never needs re-zeroing
  inv[idx] = -1;
  assign[idx] = -1;
}

// One wave per point; 4 waves/block, 4096 blocks (512 per batch).
__global__ __launch_bounds__(256) void bid_kernel(
    const float* __restrict__ xyz1, const float4* __restrict__ p2w,
    const float* __restrict__ epsp, const int* __restrict__ assign,
    u64* __restrict__ pbuf, float2* __restrict__ cand,
    float* __restrict__ bound, int it, int use_cand) {
#pragma clang fp contract(off)
  const int wave = threadIdx.x >> 6;
  const int lane = threadIdx.x & 63;
  const int blk = blockIdx.x;            // [0, 4096)
  const int b = blk & 7;                 // batch affinity (512 blocks/batch)
  const int i = ((blk >> 3) << 2) + wave;
  const int gi = b * NN + i;

  if (assign[gi] >= 0) return;           // wave-uniform early exit

  const float eps = *epsp;
  const float4* pb = p2w + b * MM;
  const float NEG_INF = __int_as_float(0xff800000);

  float v1, v2;
  int j1;

  // ---- certificate attempt: 64 candidates at current prices ----
  if (use_cand && it > 0) {
    float bnd = bound[gi];
    float2 cd = cand[((size_t)gi << 6) + lane];
    int jc = __float_as_int(cd.y);
    float4 q = pb[jc];                   // scattered, L1-resident
    v1 = cd.x - q.w;                     // negc - price: verbatim ref op
    j1 = jc;
    v2 = NEG_INF;
    for (int o = 1; o < 64; o <<= 1) {
      float ov1 = __shfl_xor(v1, o, 64);
      float ov2 = __shfl_xor(v2, o, 64);
      int oj1 = __shfl_xor(j1, o, 64);
      bool ow = (ov1 > v1) || (ov1 == v1 && oj1 < j1);
      float loser = ow ? v1 : ov1;
      v1 = ow ? ov1 : v1;
      j1 = ow ? oj1 : j1;
      v2 = fmaxf(fmaxf(v2, ov2), loser);
    }
    if (v2 > bnd) {                      // certified: top-2 is exact
      if (lane == 0) {
        float incr = (v1 - v2) + eps;
        u64 key = ((u64)(unsigned)(it + 1) << 43) |
                  ((u64)__float_as_uint(incr) << 11) |
                  (u64)(unsigned)(2047 - i);
        atomicMax(&pbuf[b * MM + j1], key);
      }
      return;
    }
  }

  // ---- full scan (it=0 / cert fail / no cand space) + refresh ----
  const float* x1p = xyz1 + (size_t)gi * 3;
  float x1 = x1p[0], y1 = x1p[1], z1 = x1p[2];
  v1 = NEG_INF;
  v2 = NEG_INF;
  j1 = 0;
  float neg1 = 0.f;                      // -c of the per-lane top-1

#pragma unroll 4
  for (int t = 0; t < MM / 64; ++t) {
    int j = (t << 6) + lane;
    float4 q = pb[j];                    // xyz + price, one 16B load
    float dx = x1 - q.x;
    float dy = y1 - q.y;
    float dz = z1 - q.z;
    float c = dx * dx;
    c = c + dy * dy;                     // contract(off): matches numpy
    c = c + dz * dz;
    float nc = -c;
    float v = nc - q.w;                  // -cost - price, reference order
    bool c1 = v > v1;
    bool c2 = v > v2;
    v2 = c1 ? v1 : (c2 ? v : v2);
    v1 = c1 ? v : v1;
    j1 = c1 ? j : j1;
    neg1 = c1 ? nc : neg1;
  }

  if (use_cand) {                        // refresh BEFORE butterfly clobbers
    cand[((size_t)gi << 6) + lane] = make_float2(neg1, __int_as_float(j1));
    float bmax = v2;                     // per-lane runner-up val
    for (int o = 1; o < 64; o <<= 1)
      bmax = fmaxf(bmax, __shfl_xor(bmax, o, 64));
    if (lane == 0) bound[gi] = bmax;     // valid forever (prices monotone)
  }

  // butterfly top-2 merge, tie-break min j on equal v1
  for (int o = 1; o < 64; o <<= 1) {
    float ov1 = __shfl_xor(v1, o, 64);
    float ov2 = __shfl_xor(v2, o, 64);
    int oj1 = __shfl_xor(j1, o, 64);
    bool ow = (ov1 > v1) || (ov1 == v1 && oj1 < j1);
    float loser = ow ? v1 : ov1;
    v1 = ow ? ov1 : v1;
    j1 = ow ? oj1 : j1;
    v2 = fmaxf(fmaxf(v2, ov2), loser);
  }
  if (lane == 0) {
    float incr = (v1 - v2) + eps;        // top1 - top2 + eps
    u64 key = ((u64)(unsigned)(it + 1) << 43) |
              ((u64)__float_as_uint(incr) << 11) |
              (u64)(unsigned)(2047 - i);
    atomicMax(&pbuf[b * MM + j1], key);
  }
}

// One thread per object: consume fresh (tag == it+1) bids; the evicted
// owner never bid and the winner owns nothing, so all assign[] writes are
// disjoint — race-free. No key reset needed (tag discipline).
__global__ __launch_bounds__(256) void update_kernel(
    const u64* __restrict__ pbuf, int* __restrict__ inv,
    int* __restrict__ assign, float4* __restrict__ p2w, int it) {
  int idx = blockIdx.x * 256 + threadIdx.x;  // [0, B*M)
  int b = idx >> 11;
  int j = idx & (MM - 1);
  u64 key = pbuf[idx];
  if ((int)(key >> 43) == it + 1) {
    float incr = __uint_as_float((unsigned)(key >> 11));
    int w = 2047 - (int)(key & 0x7FF);
    int prev = inv[idx];
    if (prev >= 0) assign[b * NN + prev] = -1;
    assign[b * NN + w] = j;
    inv[idx] = w;
    p2w[idx].w += incr;                  // the reference's single add
  }
}

__global__ __launch_bounds__(256) void final_kernel(
    const float* __restrict__ xyz1, const float4* __restrict__ p2w,
    const int* __restrict__ assign, float* __restrict__ out) {
#pragma clang fp contract(off)
  int idx = blockIdx.x * 256 + threadIdx.x;  // [0, B*N)
  int b = idx >> 11;
  int a = assign[idx];
  float d = 0.f;
  if (a >= 0) {
    float4 q = p2w[b * MM + a];
    float dx = xyz1[idx * 3 + 0] - q.x;
    float dy = xyz1[idx * 3 + 1] - q.y;
    float dz = xyz1[idx * 3 + 2] - q.z;
    d = dx * dx;
    d = d + dy * dy;
    d = d + dz * dz;
  }
  out[idx] = d;
  out[BB * NN + idx] = (float)a;         // assignment as float32 values
}

extern "C" void kernel_launch(void* const* d_in, const int* in_sizes, int n_in,
                              void* d_out, int out_size, void* d_ws, size_t ws_size,
                              hipStream_t stream) {
  const float* xyz1 = (const float*)d_in[0];
  const float* xyz2 = (const float*)d_in[1];
  const float* eps  = (const float*)d_in[2];
  // d_in[3] = iters (fixed at 20 by setup_inputs); hard-coded for capture.
  float* out = (float*)d_out;

  char* ws = (char*)d_ws;
  float4* p2w = (float4*)ws;
  u64* pbuf = (u64*)(ws + 262144);
  int* inv = (int*)(ws + 393216);
  int* assign = (int*)(ws + 458752);
  float* bound = (float*)(ws + 524288);
  float2* cand = (float2*)(ws + 589824);
  const int use_cand = (ws_size >= 589824ull + 8388608ull) ? 1 : 0;

  pack_kernel<<<BB * MM / 256, 256, 0, stream>>>(xyz2, p2w, pbuf, inv,
                                                 assign);
  for (int it = 0; it < ITERS; ++it) {
    bid_kernel<<<BB * NN / 4, 256, 0, stream>>>(xyz1, p2w, eps, assign,
                                                pbuf, cand, bound, it,
                                                use_cand);
    update_kernel<<<BB * MM / 256, 256, 0, stream>>>(pbuf, inv, assign,
                                                     p2w, it);
  }
  final_kernel<<<BB * NN / 256, 256, 0, stream>>>(xyz1, p2w, assign, out);
}